// Round 1
// baseline (1394.598 us; speedup 1.0000x reference)
//
#include <hip/hip_runtime.h>
#include <math.h>

#define NN 50000
#define EE 800000
#define FIN 128
#define NH 5
#define CC 32
#define HC 160
#define NG 64

__device__ __forceinline__ float lrelu(float x, float s) { return x >= 0.f ? x : s * x; }

// ---------------------------------------------------------------- zero scratch
__global__ void zero_kernel(int* deg, float* easum, float* pooled, int* gcnt) {
    int i = blockIdx.x * 256 + threadIdx.x;
    if (i < NN) { deg[i] = 0; easum[i] = 0.f; }
    if (i < NG * HC) pooled[i] = 0.f;
    if (i < NG) gcnt[i] = 0;
}

// ------------------------------------------- in-degree histogram + edge_attr sum
__global__ void hist_kernel(const int* __restrict__ ei, const float* __restrict__ ea,
                            int* deg, float* easum, const int* __restrict__ batch, int* gcnt) {
    int e = blockIdx.x * 256 + threadIdx.x;
    if (e < NN) atomicAdd(&gcnt[batch[e]], 1);
    if (e >= EE) return;
    int d = ei[EE + e];
    atomicAdd(&deg[d], 1);
    atomicAdd(&easum[d], ea[e]);
}

// ---------------------------------------------------- exclusive scan (1 block)
__global__ void scan_kernel(const int* __restrict__ deg, int* off, int* cursor) {
    __shared__ int wsum[16];
    __shared__ int carry_s;
    int tid = threadIdx.x;
    int lane = tid & 63, wid = tid >> 6;
    if (tid == 0) { carry_s = 0; off[0] = 0; }
    __syncthreads();
    for (int base = 0; base < NN; base += 1024) {
        int i = base + tid;
        int v = (i < NN) ? deg[i] : 0;
        int x = v;
        for (int o = 1; o < 64; o <<= 1) {
            int t = __shfl_up(x, o, 64);
            if (lane >= o) x += t;
        }
        if (lane == 63) wsum[wid] = x;
        __syncthreads();
        if (tid == 0) {
            int acc = carry_s;
            for (int w = 0; w < 16; w++) { int t = wsum[w]; wsum[w] = acc; acc += t; }
            carry_s = acc;
        }
        __syncthreads();
        int incl = x + wsum[wid];
        if (i < NN) { off[i + 1] = incl; cursor[i] = incl - v; }
        __syncthreads();
    }
}

// --------------------------------------------------- counting-sort edge scatter
__global__ void scatter_kernel(const int* __restrict__ ei, const float* __restrict__ ea,
                               int* cursor, int* ssrc, int* seid, float* sea) {
    int e = blockIdx.x * 256 + threadIdx.x;
    if (e >= EE) return;
    int d = ei[EE + e];
    int p = atomicAdd(&cursor[d], 1);
    ssrc[p] = ei[e];
    seid[p] = e;
    sea[p] = ea[e];
}

// -------------------------------------- s[h] = dot(we[h*32: ], ae[h]) per layer
__global__ void preps_kernel(const float* we1, const float* ae1,
                             const float* we2, const float* ae2, float* s_out) {
    int tid = threadIdx.x;
    if (tid < 10) {
        const float* we = (tid < 5) ? we1 : we2;
        const float* ae = (tid < 5) ? ae1 : ae2;
        int h = tid % 5;
        float s = 0.f;
        for (int c = 0; c < 32; c++) s += we[h * 32 + c] * ae[h * 32 + c];
        s_out[tid] = s;
    }
}

// -------------------------------------------------- h = A @ W  (K = 128 or 160)
template <int K>
__global__ __launch_bounds__(160) void gemm_kernel(const float* __restrict__ A,
                                                   const float* __restrict__ W,
                                                   float* __restrict__ out) {
    __shared__ __align__(16) float xs[K][16];
    int j = threadIdx.x;
    int base = blockIdx.x * 16;
    for (int idx = j; idx < 16 * K; idx += 160) {
        int r = idx / K, k = idx - r * K;
        xs[k][r] = A[(size_t)(base + r) * K + k];
    }
    __syncthreads();
    float acc[16];
#pragma unroll
    for (int r = 0; r < 16; r++) acc[r] = 0.f;
    for (int k = 0; k < K; k++) {
        float wv = W[k * HC + j];
        const float4* row = reinterpret_cast<const float4*>(&xs[k][0]);
        float4 q0 = row[0], q1 = row[1], q2 = row[2], q3 = row[3];
        acc[0] += q0.x * wv;  acc[1] += q0.y * wv;  acc[2] += q0.z * wv;  acc[3] += q0.w * wv;
        acc[4] += q1.x * wv;  acc[5] += q1.y * wv;  acc[6] += q1.z * wv;  acc[7] += q1.w * wv;
        acc[8] += q2.x * wv;  acc[9] += q2.y * wv;  acc[10] += q2.z * wv; acc[11] += q2.w * wv;
        acc[12] += q3.x * wv; acc[13] += q3.y * wv; acc[14] += q3.z * wv; acc[15] += q3.w * wv;
    }
#pragma unroll
    for (int r = 0; r < 16; r++) out[(size_t)(base + r) * HC + j] = acc[r];
}

// ------------------------------------ per-(node,head) attention dot products
__global__ void alsd_kernel(const float* __restrict__ h, const float* __restrict__ a_s,
                            const float* __restrict__ a_d, float* al_s, float* al_d) {
    int i = blockIdx.x * 256 + threadIdx.x;
    if (i >= NN * NH) return;
    int n = i / NH, hd = i - n * NH;
    const float* hp = h + (size_t)n * HC + hd * 32;
    float ss = 0.f, sd = 0.f;
    for (int c = 0; c < 32; c++) {
        float hv = hp[c];
        ss += hv * a_s[hd * 32 + c];
        sd += hv * a_d[hd * 32 + c];
    }
    al_s[i] = ss;
    al_d[i] = sd;
}

// ------------- per-node: segment softmax + weighted gather + bias/lrelu/LN
__global__ __launch_bounds__(192) void aggregate_kernel(
    const int* __restrict__ soff, const int* __restrict__ ssrc,
    const int* __restrict__ seid, const float* __restrict__ sea,
    const float* __restrict__ hfeat, const float* __restrict__ al_s,
    const float* __restrict__ al_d, const float* __restrict__ easum,
    const float* __restrict__ s_e, const float* __restrict__ bias,
    const float* __restrict__ g_ln, const float* __restrict__ b_ln,
    float* __restrict__ alpha_out, float* __restrict__ x_out) {
    int n = blockIdx.x;
    int tid = threadIdx.x;
    int lane = tid & 63, wid = tid >> 6;
    int s0 = soff[n];
    int deg = soff[n + 1] - s0;
    int items = deg + 1;

    __shared__ float sm[NH], sden[NH];
    __shared__ float wred[16], wred2[16];
    __shared__ float stat[2];

    float ad[NH], se[NH];
#pragma unroll
    for (int h = 0; h < NH; h++) { ad[h] = al_d[n * NH + h]; se[h] = s_e[h]; }
    float emean = easum[n] / fmaxf((float)deg, 1.f);

    // pass A: per-head max
    float lm[NH];
#pragma unroll
    for (int h = 0; h < NH; h++) lm[h] = -3.0e38f;
    for (int i = tid; i < items; i += 192) {
        int src; float ea;
        if (i < deg) { src = ssrc[s0 + i]; ea = sea[s0 + i]; }
        else         { src = n; ea = emean; }
#pragma unroll
        for (int h = 0; h < NH; h++) {
            float r = lrelu(al_s[src * NH + h] + ad[h] + ea * se[h], 0.2f);
            lm[h] = fmaxf(lm[h], r);
        }
    }
#pragma unroll
    for (int h = 0; h < NH; h++)
        for (int o = 32; o >= 1; o >>= 1) lm[h] = fmaxf(lm[h], __shfl_down(lm[h], o, 64));
    if (lane == 0) {
#pragma unroll
        for (int h = 0; h < NH; h++) wred[wid * NH + h] = lm[h];
    }
    __syncthreads();
    if (tid < NH) sm[tid] = fmaxf(fmaxf(wred[tid], wred[NH + tid]), wred[2 * NH + tid]);
    __syncthreads();

    // pass B: per-head sum of exp
    float lsum[NH] = {0.f, 0.f, 0.f, 0.f, 0.f};
    for (int i = tid; i < items; i += 192) {
        int src; float ea;
        if (i < deg) { src = ssrc[s0 + i]; ea = sea[s0 + i]; }
        else         { src = n; ea = emean; }
#pragma unroll
        for (int h = 0; h < NH; h++) {
            float r = lrelu(al_s[src * NH + h] + ad[h] + ea * se[h], 0.2f);
            lsum[h] += expf(r - sm[h]);
        }
    }
#pragma unroll
    for (int h = 0; h < NH; h++)
        for (int o = 32; o >= 1; o >>= 1) lsum[h] += __shfl_down(lsum[h], o, 64);
    if (lane == 0) {
#pragma unroll
        for (int h = 0; h < NH; h++) wred2[wid * NH + h] = lsum[h];
    }
    __syncthreads();
    if (tid < NH) sden[tid] = wred2[tid] + wred2[NH + tid] + wred2[2 * NH + tid];
    __syncthreads();

    // pass C: channel-parallel weighted gather + alpha writeback
    float v = 0.f;
    if (tid < HC) {
        int c = tid, hd = c >> 5;
        float mh = sm[hd], invd = 1.f / sden[hd], adh = ad[hd], seh = se[hd];
        float acc = 0.f;
        for (int i = 0; i < items; i++) {
            int src; float ea; int opos;
            if (i < deg) { int p = s0 + i; src = ssrc[p]; ea = sea[p]; opos = seid[p]; }
            else         { src = n; ea = emean; opos = EE + n; }
            float r = lrelu(al_s[src * NH + hd] + adh + ea * seh, 0.2f);
            float w = expf(r - mh) * invd;
            if ((c & 31) == 0) alpha_out[(size_t)opos * NH + hd] = w;
            acc += w * hfeat[(size_t)src * HC + c];
        }
        v = lrelu(acc + bias[c], 0.01f);
    }
    // fused LayerNorm across the 160 channels
    float p1 = (tid < HC) ? v : 0.f;
    float p2 = p1 * p1;
    for (int o = 32; o >= 1; o >>= 1) {
        p1 += __shfl_down(p1, o, 64);
        p2 += __shfl_down(p2, o, 64);
    }
    if (lane == 0) { wred[wid] = p1; wred[8 + wid] = p2; }
    __syncthreads();
    if (tid == 0) {
        float s1 = wred[0] + wred[1] + wred[2];
        float s2 = wred[8] + wred[9] + wred[10];
        float mean = s1 / (float)HC;
        float var = s2 / (float)HC - mean * mean;
        stat[0] = mean;
        stat[1] = rsqrtf(var + 1e-5f);
    }
    __syncthreads();
    if (tid < HC)
        x_out[(size_t)n * HC + tid] = (v - stat[0]) * stat[1] * g_ln[tid] + b_ln[tid];
}

// -------- x3 = lrelu(x2 @ mw + mb); fused pooled partial sums (batch sorted)
__global__ __launch_bounds__(160) void gemm3_kernel(const float* A, const float* __restrict__ W,
                                                    const float* __restrict__ bias,
                                                    const int* __restrict__ batch,
                                                    float* x3, float* pooled) {
    __shared__ __align__(16) float xs[HC][16];
    __shared__ int bt[16];
    int j = threadIdx.x;
    int base = blockIdx.x * 16;
    for (int idx = j; idx < 16 * HC; idx += 160) {
        int r = idx / HC, k = idx - r * HC;
        xs[k][r] = A[(size_t)(base + r) * HC + k];
    }
    if (j < 16) bt[j] = batch[base + j];
    __syncthreads();
    float acc[16];
#pragma unroll
    for (int r = 0; r < 16; r++) acc[r] = 0.f;
    for (int k = 0; k < HC; k++) {
        float wv = W[k * HC + j];
        const float4* row = reinterpret_cast<const float4*>(&xs[k][0]);
        float4 q0 = row[0], q1 = row[1], q2 = row[2], q3 = row[3];
        acc[0] += q0.x * wv;  acc[1] += q0.y * wv;  acc[2] += q0.z * wv;  acc[3] += q0.w * wv;
        acc[4] += q1.x * wv;  acc[5] += q1.y * wv;  acc[6] += q1.z * wv;  acc[7] += q1.w * wv;
        acc[8] += q2.x * wv;  acc[9] += q2.y * wv;  acc[10] += q2.z * wv; acc[11] += q2.w * wv;
        acc[12] += q3.x * wv; acc[13] += q3.y * wv; acc[14] += q3.z * wv; acc[15] += q3.w * wv;
    }
    float bj = bias[j];
    float run = 0.f;
    int g = bt[0];
#pragma unroll
    for (int r = 0; r < 16; r++) {
        float v = lrelu(acc[r] + bj, 0.01f);
        x3[(size_t)(base + r) * HC + j] = v;
        int gb = bt[r];
        if (gb != g) { atomicAdd(&pooled[g * HC + j], run); run = 0.f; g = gb; }
        run += v;
    }
    atomicAdd(&pooled[g * HC + j], run);
}

__global__ void pooldiv_kernel(const float* __restrict__ psum, const int* __restrict__ gcnt,
                               float* pooled_out) {
    int i = blockIdx.x * 256 + threadIdx.x;
    if (i < NG * HC) pooled_out[i] = psum[i] / fmaxf((float)gcnt[i / HC], 1.f);
}

// ---------------------------------------------------------------------- launch
extern "C" void kernel_launch(void* const* d_in, const int* in_sizes, int n_in,
                              void* d_out, int out_size, void* d_ws, size_t ws_size,
                              hipStream_t stream) {
    const float* x    = (const float*)d_in[0];
    const int*   ei   = (const int*)d_in[1];
    const float* ea   = (const float*)d_in[2];
    const int*   batch= (const int*)d_in[3];
    const float* w1   = (const float*)d_in[4];
    const float* we1  = (const float*)d_in[5];
    const float* as1  = (const float*)d_in[6];
    const float* ad1  = (const float*)d_in[7];
    const float* ae1  = (const float*)d_in[8];
    const float* b1   = (const float*)d_in[9];
    const float* w2   = (const float*)d_in[10];
    const float* we2  = (const float*)d_in[11];
    const float* as2  = (const float*)d_in[12];
    const float* ad2  = (const float*)d_in[13];
    const float* ae2  = (const float*)d_in[14];
    const float* b2   = (const float*)d_in[15];
    const float* ln1g = (const float*)d_in[16];
    const float* ln1b = (const float*)d_in[17];
    const float* ln2g = (const float*)d_in[18];
    const float* ln2b = (const float*)d_in[19];
    const float* mw   = (const float*)d_in[20];
    const float* mb   = (const float*)d_in[21];

    float* out = (float*)d_out;
    float* x12 = out;                                 // x1/x2 scratch in x3 region
    float* pooled_out = out + (size_t)NN * HC;
    float* a1 = pooled_out + NG * HC;
    float* a2 = a1 + (size_t)(EE + NN) * NH;

    char* wp = (char*)d_ws;
    auto alloc = [&](size_t bytes) {
        void* p = (void*)wp;
        wp += (bytes + 255) & ~(size_t)255;
        return p;
    };
    float* hbuf  = (float*)alloc((size_t)NN * HC * 4);   // 32 MB
    float* als   = (float*)alloc((size_t)NN * NH * 4);
    float* ald   = (float*)alloc((size_t)NN * NH * 4);
    int*   deg   = (int*)alloc((size_t)NN * 4);
    float* easum = (float*)alloc((size_t)NN * 4);
    int*   soff  = (int*)alloc((size_t)(NN + 1) * 4);
    int*   cursor= (int*)alloc((size_t)NN * 4);
    int*   ssrc  = (int*)alloc((size_t)EE * 4);
    int*   seid  = (int*)alloc((size_t)EE * 4);
    float* seab  = (float*)alloc((size_t)EE * 4);
    float* sbuf  = (float*)alloc(64);
    float* psum  = (float*)alloc((size_t)NG * HC * 4);
    int*   gcnt  = (int*)alloc((size_t)NG * 4);

    zero_kernel<<<196, 256, 0, stream>>>(deg, easum, psum, gcnt);
    hist_kernel<<<3125, 256, 0, stream>>>(ei, ea, deg, easum, batch, gcnt);
    scan_kernel<<<1, 1024, 0, stream>>>(deg, soff, cursor);
    scatter_kernel<<<3125, 256, 0, stream>>>(ei, ea, cursor, ssrc, seid, seab);
    preps_kernel<<<1, 64, 0, stream>>>(we1, ae1, we2, ae2, sbuf);

    gemm_kernel<128><<<3125, 160, 0, stream>>>(x, w1, hbuf);
    alsd_kernel<<<977, 256, 0, stream>>>(hbuf, as1, ad1, als, ald);
    aggregate_kernel<<<NN, 192, 0, stream>>>(soff, ssrc, seid, seab, hbuf, als, ald,
                                             easum, sbuf, b1, ln1g, ln1b, a1, x12);

    gemm_kernel<160><<<3125, 160, 0, stream>>>(x12, w2, hbuf);
    alsd_kernel<<<977, 256, 0, stream>>>(hbuf, as2, ad2, als, ald);
    aggregate_kernel<<<NN, 192, 0, stream>>>(soff, ssrc, seid, seab, hbuf, als, ald,
                                             easum, sbuf + 5, b2, ln2g, ln2b, a2, x12);

    gemm3_kernel<<<3125, 160, 0, stream>>>(x12, mw, mb, batch, out, psum);
    pooldiv_kernel<<<40, 256, 0, stream>>>(psum, gcnt, pooled_out);
}

// Round 2
// 982.550 us; speedup vs baseline: 1.4194x; 1.4194x over previous
//
#include <hip/hip_runtime.h>
#include <math.h>

#define NN 50000
#define EE 800000
#define FIN 128
#define NH 5
#define CC 32
#define HC 160
#define NG 64
#define CHUNK 384

__device__ __forceinline__ float lrelu(float x, float s) { return x >= 0.f ? x : s * x; }

// ---------------------------------------------------------------- zero scratch
__global__ void zero_kernel(int* deg, float* easum, float* pooled, int* gcnt) {
    int i = blockIdx.x * 256 + threadIdx.x;
    if (i < NN) { deg[i] = 0; easum[i] = 0.f; }
    if (i < NG * HC) pooled[i] = 0.f;
    if (i < NG) gcnt[i] = 0;
}

// ------------------------------------------- in-degree histogram + edge_attr sum
__global__ void hist_kernel(const int* __restrict__ ei, const float* __restrict__ ea,
                            int* deg, float* easum, const int* __restrict__ batch, int* gcnt) {
    int e = blockIdx.x * 256 + threadIdx.x;
    if (e < NN) atomicAdd(&gcnt[batch[e]], 1);
    if (e >= EE) return;
    int d = ei[EE + e];
    atomicAdd(&deg[d], 1);
    atomicAdd(&easum[d], ea[e]);
}

// ------------------------------------------------------- 3-phase parallel scan
__global__ void scan1_kernel(const int* __restrict__ deg, int* bsum) {
    __shared__ int ws[4];
    int tid = threadIdx.x, lane = tid & 63, wid = tid >> 6;
    int i = blockIdx.x * 256 + tid;
    int v = (i < NN) ? deg[i] : 0;
    for (int o = 32; o >= 1; o >>= 1) v += __shfl_down(v, o, 64);
    if (lane == 0) ws[wid] = v;
    __syncthreads();
    if (tid == 0) bsum[blockIdx.x] = ws[0] + ws[1] + ws[2] + ws[3];
}

__global__ void scan2_kernel(int* bsum, int* boff) {   // 1 block, 256 thr, 196 ents
    __shared__ int ws[4];
    int tid = threadIdx.x, lane = tid & 63, wid = tid >> 6;
    int v = (tid < 196) ? bsum[tid] : 0;
    int x = v;
    for (int o = 1; o < 64; o <<= 1) {
        int t = __shfl_up(x, o, 64);
        if (lane >= o) x += t;
    }
    if (lane == 63) ws[wid] = x;
    __syncthreads();
    if (tid == 0) {
        int acc = 0;
        for (int w = 0; w < 4; w++) { int t = ws[w]; ws[w] = acc; acc += t; }
    }
    __syncthreads();
    if (tid < 196) boff[tid] = x + ws[wid] - v;
}

__global__ void scan3_kernel(const int* __restrict__ deg, const int* __restrict__ boff,
                             int* off, int* cursor) {
    __shared__ int ws[4];
    int tid = threadIdx.x, lane = tid & 63, wid = tid >> 6;
    int i = blockIdx.x * 256 + tid;
    int v = (i < NN) ? deg[i] : 0;
    int x = v;
    for (int o = 1; o < 64; o <<= 1) {
        int t = __shfl_up(x, o, 64);
        if (lane >= o) x += t;
    }
    if (lane == 63) ws[wid] = x;
    __syncthreads();
    if (tid == 0) {
        int acc = 0;
        for (int w = 0; w < 4; w++) { int t = ws[w]; ws[w] = acc; acc += t; }
    }
    __syncthreads();
    int incl = x + ws[wid] + boff[blockIdx.x];
    if (i < NN) { off[i + 1] = incl; cursor[i] = incl - v; }
    if (i == 0) off[0] = 0;
}

// --------------------------------------------------- counting-sort edge scatter
__global__ void scatter_kernel(const int* __restrict__ ei, const float* __restrict__ ea,
                               int* cursor, int* ssrc, int* seid, float* sea) {
    int e = blockIdx.x * 256 + threadIdx.x;
    if (e >= EE) return;
    int d = ei[EE + e];
    int p = atomicAdd(&cursor[d], 1);
    ssrc[p] = ei[e];
    seid[p] = e;
    sea[p] = ea[e];
}

// -------------------------------------- s[h] = dot(we[h*32: ], ae[h]) per layer
__global__ void preps_kernel(const float* we1, const float* ae1,
                             const float* we2, const float* ae2, float* s_out) {
    int tid = threadIdx.x;
    if (tid < 10) {
        const float* we = (tid < 5) ? we1 : we2;
        const float* ae = (tid < 5) ? ae1 : ae2;
        int h = tid % 5;
        float s = 0.f;
        for (int c = 0; c < 32; c++) s += we[h * 32 + c] * ae[h * 32 + c];
        s_out[tid] = s;
    }
}

// ---------------- h = A @ W  (K = 128 or 160), fused per-(node,head) att dots
template <int K>
__global__ __launch_bounds__(160) void gemm_kernel(const float* __restrict__ A,
                                                   const float* __restrict__ W,
                                                   const float* __restrict__ a_s,
                                                   const float* __restrict__ a_d,
                                                   float* __restrict__ out,
                                                   float* al_s, float* al_d) {
    __shared__ __align__(16) float xs[K][16];
    __shared__ float hs[16][HC + 1];
    int j = threadIdx.x;
    int base = blockIdx.x * 16;
    for (int idx = j; idx < 16 * K; idx += 160) {
        int r = idx / K, k = idx - r * K;
        xs[k][r] = A[(size_t)(base + r) * K + k];
    }
    __syncthreads();
    float acc[16];
#pragma unroll
    for (int r = 0; r < 16; r++) acc[r] = 0.f;
    for (int k = 0; k < K; k++) {
        float wv = W[k * HC + j];
        const float4* row = reinterpret_cast<const float4*>(&xs[k][0]);
        float4 q0 = row[0], q1 = row[1], q2 = row[2], q3 = row[3];
        acc[0] += q0.x * wv;  acc[1] += q0.y * wv;  acc[2] += q0.z * wv;  acc[3] += q0.w * wv;
        acc[4] += q1.x * wv;  acc[5] += q1.y * wv;  acc[6] += q1.z * wv;  acc[7] += q1.w * wv;
        acc[8] += q2.x * wv;  acc[9] += q2.y * wv;  acc[10] += q2.z * wv; acc[11] += q2.w * wv;
        acc[12] += q3.x * wv; acc[13] += q3.y * wv; acc[14] += q3.z * wv; acc[15] += q3.w * wv;
    }
#pragma unroll
    for (int r = 0; r < 16; r++) {
        out[(size_t)(base + r) * HC + j] = acc[r];
        hs[r][j] = acc[r];
    }
    __syncthreads();
    // 160 tasks: 16 rows x 5 heads x {src,dst}
    {
        int r = j / 10, rem = j - r * 10;
        int hd = rem >> 1, sd = rem & 1;
        const float* av = sd ? a_d : a_s;
        float s = 0.f;
#pragma unroll
        for (int c = 0; c < 32; c++) s += hs[r][hd * 32 + c] * av[hd * 32 + c];
        float* dst = sd ? al_d : al_s;
        dst[(base + r) * NH + hd] = s;
    }
}

// ------------- per-node: segment softmax + weighted gather + bias/lrelu/LN
__global__ __launch_bounds__(192) void aggregate_kernel(
    const int* __restrict__ soff, const int* __restrict__ ssrc,
    const int* __restrict__ seid, const float* __restrict__ sea,
    const float* __restrict__ hfeat, const float* __restrict__ al_s,
    const float* __restrict__ al_d, const float* __restrict__ easum,
    const float* __restrict__ s_e, const float* __restrict__ bias,
    const float* __restrict__ g_ln, const float* __restrict__ b_ln,
    float* __restrict__ alpha_out, float* __restrict__ x_out) {
    int n = blockIdx.x;
    int tid = threadIdx.x;
    int lane = tid & 63, wid = tid >> 6;
    int s0 = soff[n];
    int deg = soff[n + 1] - s0;
    int items = deg + 1;

    __shared__ float w_sh[CHUNK * NH];
    __shared__ int isrc_sh[CHUNK];
    __shared__ float sm[NH], sden[NH], sdinv[NH];
    __shared__ float wred[16], wred2[16];
    __shared__ float stat[2];

    float ad[NH], se[NH];
#pragma unroll
    for (int h = 0; h < NH; h++) { ad[h] = al_d[n * NH + h]; se[h] = s_e[h]; }
    float emean = easum[n] / fmaxf((float)deg, 1.f);

    float v = 0.f;

    if (items <= CHUNK) {
        // ---- fast path: logits once into LDS ----
        float lm[NH];
#pragma unroll
        for (int h = 0; h < NH; h++) lm[h] = -3.0e38f;
        for (int i = tid; i < items; i += 192) {
            int src; float ea;
            if (i < deg) { src = ssrc[s0 + i]; ea = sea[s0 + i]; }
            else         { src = n; ea = emean; }
            isrc_sh[i] = src;
#pragma unroll
            for (int h = 0; h < NH; h++) {
                float r = lrelu(al_s[src * NH + h] + ad[h] + ea * se[h], 0.2f);
                w_sh[i * NH + h] = r;
                lm[h] = fmaxf(lm[h], r);
            }
        }
#pragma unroll
        for (int h = 0; h < NH; h++)
            for (int o = 32; o >= 1; o >>= 1) lm[h] = fmaxf(lm[h], __shfl_down(lm[h], o, 64));
        if (lane == 0) {
#pragma unroll
            for (int h = 0; h < NH; h++) wred[wid * NH + h] = lm[h];
        }
        __syncthreads();
        if (tid < NH) sm[tid] = fmaxf(fmaxf(wred[tid], wred[NH + tid]), wred[2 * NH + tid]);
        __syncthreads();

        float lsum[NH] = {0.f, 0.f, 0.f, 0.f, 0.f};
        for (int i = tid; i < items; i += 192) {
#pragma unroll
            for (int h = 0; h < NH; h++) {
                float w = expf(w_sh[i * NH + h] - sm[h]);
                w_sh[i * NH + h] = w;
                lsum[h] += w;
            }
        }
#pragma unroll
        for (int h = 0; h < NH; h++)
            for (int o = 32; o >= 1; o >>= 1) lsum[h] += __shfl_down(lsum[h], o, 64);
        if (lane == 0) {
#pragma unroll
            for (int h = 0; h < NH; h++) wred2[wid * NH + h] = lsum[h];
        }
        __syncthreads();
        if (tid < NH) {
            float d = wred2[tid] + wred2[NH + tid] + wred2[2 * NH + tid];
            sden[tid] = d;
            sdinv[tid] = 1.f / d;
        }
        __syncthreads();

        // normalize in LDS + write alpha (item-parallel)
        for (int i = tid; i < items; i += 192) {
            int opos = (i < deg) ? seid[s0 + i] : (EE + n);
#pragma unroll
            for (int h = 0; h < NH; h++) {
                float w = w_sh[i * NH + h] * sdinv[h];
                w_sh[i * NH + h] = w;
                alpha_out[(size_t)opos * NH + h] = w;
            }
        }
        __syncthreads();

        // channel-parallel accumulate from LDS weights
        if (tid < HC) {
            int c = tid, hd = c >> 5;
            float acc = 0.f;
            for (int i = 0; i < items; i++) {
                int src = isrc_sh[i];
                acc += w_sh[i * NH + hd] * hfeat[(size_t)src * HC + c];
            }
            v = lrelu(acc + bias[c], 0.01f);
        }
    } else {
        // ---- slow path (degree > CHUNK-1): streaming recompute ----
        float lm[NH];
#pragma unroll
        for (int h = 0; h < NH; h++) lm[h] = -3.0e38f;
        for (int i = tid; i < items; i += 192) {
            int src; float ea;
            if (i < deg) { src = ssrc[s0 + i]; ea = sea[s0 + i]; }
            else         { src = n; ea = emean; }
#pragma unroll
            for (int h = 0; h < NH; h++) {
                float r = lrelu(al_s[src * NH + h] + ad[h] + ea * se[h], 0.2f);
                lm[h] = fmaxf(lm[h], r);
            }
        }
#pragma unroll
        for (int h = 0; h < NH; h++)
            for (int o = 32; o >= 1; o >>= 1) lm[h] = fmaxf(lm[h], __shfl_down(lm[h], o, 64));
        if (lane == 0) {
#pragma unroll
            for (int h = 0; h < NH; h++) wred[wid * NH + h] = lm[h];
        }
        __syncthreads();
        if (tid < NH) sm[tid] = fmaxf(fmaxf(wred[tid], wred[NH + tid]), wred[2 * NH + tid]);
        __syncthreads();

        float lsum[NH] = {0.f, 0.f, 0.f, 0.f, 0.f};
        for (int i = tid; i < items; i += 192) {
            int src; float ea;
            if (i < deg) { src = ssrc[s0 + i]; ea = sea[s0 + i]; }
            else         { src = n; ea = emean; }
#pragma unroll
            for (int h = 0; h < NH; h++) {
                float r = lrelu(al_s[src * NH + h] + ad[h] + ea * se[h], 0.2f);
                lsum[h] += expf(r - sm[h]);
            }
        }
#pragma unroll
        for (int h = 0; h < NH; h++)
            for (int o = 32; o >= 1; o >>= 1) lsum[h] += __shfl_down(lsum[h], o, 64);
        if (lane == 0) {
#pragma unroll
            for (int h = 0; h < NH; h++) wred2[wid * NH + h] = lsum[h];
        }
        __syncthreads();
        if (tid < NH) sden[tid] = wred2[tid] + wred2[NH + tid] + wred2[2 * NH + tid];
        __syncthreads();

        if (tid < HC) {
            int c = tid, hd = c >> 5;
            float mh = sm[hd], invd = 1.f / sden[hd], adh = ad[hd], seh = se[hd];
            float acc = 0.f;
            for (int i = 0; i < items; i++) {
                int src; float ea; int opos;
                if (i < deg) { int p = s0 + i; src = ssrc[p]; ea = sea[p]; opos = seid[p]; }
                else         { src = n; ea = emean; opos = EE + n; }
                float r = lrelu(al_s[src * NH + hd] + adh + ea * seh, 0.2f);
                float w = expf(r - mh) * invd;
                if ((c & 31) == 0) alpha_out[(size_t)opos * NH + hd] = w;
                acc += w * hfeat[(size_t)src * HC + c];
            }
            v = lrelu(acc + bias[c], 0.01f);
        }
    }

    // fused LayerNorm across the 160 channels
    float p1 = (tid < HC) ? v : 0.f;
    float p2 = p1 * p1;
    for (int o = 32; o >= 1; o >>= 1) {
        p1 += __shfl_down(p1, o, 64);
        p2 += __shfl_down(p2, o, 64);
    }
    if (lane == 0) { wred[wid] = p1; wred[8 + wid] = p2; }
    __syncthreads();
    if (tid == 0) {
        float s1 = wred[0] + wred[1] + wred[2];
        float s2 = wred[8] + wred[9] + wred[10];
        float mean = s1 / (float)HC;
        float var = s2 / (float)HC - mean * mean;
        stat[0] = mean;
        stat[1] = rsqrtf(var + 1e-5f);
    }
    __syncthreads();
    if (tid < HC)
        x_out[(size_t)n * HC + tid] = (v - stat[0]) * stat[1] * g_ln[tid] + b_ln[tid];
}

// -------- x3 = lrelu(x2 @ mw + mb); fused pooled partial sums (batch sorted)
__global__ __launch_bounds__(160) void gemm3_kernel(const float* A, const float* __restrict__ W,
                                                    const float* __restrict__ bias,
                                                    const int* __restrict__ batch,
                                                    float* x3, float* pooled) {
    __shared__ __align__(16) float xs[HC][16];
    __shared__ int bt[16];
    int j = threadIdx.x;
    int base = blockIdx.x * 16;
    for (int idx = j; idx < 16 * HC; idx += 160) {
        int r = idx / HC, k = idx - r * HC;
        xs[k][r] = A[(size_t)(base + r) * HC + k];
    }
    if (j < 16) bt[j] = batch[base + j];
    __syncthreads();
    float acc[16];
#pragma unroll
    for (int r = 0; r < 16; r++) acc[r] = 0.f;
    for (int k = 0; k < HC; k++) {
        float wv = W[k * HC + j];
        const float4* row = reinterpret_cast<const float4*>(&xs[k][0]);
        float4 q0 = row[0], q1 = row[1], q2 = row[2], q3 = row[3];
        acc[0] += q0.x * wv;  acc[1] += q0.y * wv;  acc[2] += q0.z * wv;  acc[3] += q0.w * wv;
        acc[4] += q1.x * wv;  acc[5] += q1.y * wv;  acc[6] += q1.z * wv;  acc[7] += q1.w * wv;
        acc[8] += q2.x * wv;  acc[9] += q2.y * wv;  acc[10] += q2.z * wv; acc[11] += q2.w * wv;
        acc[12] += q3.x * wv; acc[13] += q3.y * wv; acc[14] += q3.z * wv; acc[15] += q3.w * wv;
    }
    float bj = bias[j];
    float run = 0.f;
    int g = bt[0];
#pragma unroll
    for (int r = 0; r < 16; r++) {
        float v = lrelu(acc[r] + bj, 0.01f);
        x3[(size_t)(base + r) * HC + j] = v;
        int gb = bt[r];
        if (gb != g) { atomicAdd(&pooled[g * HC + j], run); run = 0.f; g = gb; }
        run += v;
    }
    atomicAdd(&pooled[g * HC + j], run);
}

__global__ void pooldiv_kernel(const float* __restrict__ psum, const int* __restrict__ gcnt,
                               float* pooled_out) {
    int i = blockIdx.x * 256 + threadIdx.x;
    if (i < NG * HC) pooled_out[i] = psum[i] / fmaxf((float)gcnt[i / HC], 1.f);
}

// ---------------------------------------------------------------------- launch
extern "C" void kernel_launch(void* const* d_in, const int* in_sizes, int n_in,
                              void* d_out, int out_size, void* d_ws, size_t ws_size,
                              hipStream_t stream) {
    const float* x    = (const float*)d_in[0];
    const int*   ei   = (const int*)d_in[1];
    const float* ea   = (const float*)d_in[2];
    const int*   batch= (const int*)d_in[3];
    const float* w1   = (const float*)d_in[4];
    const float* we1  = (const float*)d_in[5];
    const float* as1  = (const float*)d_in[6];
    const float* ad1  = (const float*)d_in[7];
    const float* ae1  = (const float*)d_in[8];
    const float* b1   = (const float*)d_in[9];
    const float* w2   = (const float*)d_in[10];
    const float* we2  = (const float*)d_in[11];
    const float* as2  = (const float*)d_in[12];
    const float* ad2  = (const float*)d_in[13];
    const float* ae2  = (const float*)d_in[14];
    const float* b2   = (const float*)d_in[15];
    const float* ln1g = (const float*)d_in[16];
    const float* ln1b = (const float*)d_in[17];
    const float* ln2g = (const float*)d_in[18];
    const float* ln2b = (const float*)d_in[19];
    const float* mw   = (const float*)d_in[20];
    const float* mb   = (const float*)d_in[21];

    float* out = (float*)d_out;
    float* x12 = out;                                 // x1/x2 scratch in x3 region
    float* pooled_out = out + (size_t)NN * HC;
    float* a1 = pooled_out + NG * HC;
    float* a2 = a1 + (size_t)(EE + NN) * NH;

    char* wp = (char*)d_ws;
    auto alloc = [&](size_t bytes) {
        void* p = (void*)wp;
        wp += (bytes + 255) & ~(size_t)255;
        return p;
    };
    float* hbuf  = (float*)alloc((size_t)NN * HC * 4);   // 32 MB
    float* als   = (float*)alloc((size_t)NN * NH * 4);
    float* ald   = (float*)alloc((size_t)NN * NH * 4);
    int*   deg   = (int*)alloc((size_t)NN * 4);
    float* easum = (float*)alloc((size_t)NN * 4);
    int*   soff  = (int*)alloc((size_t)(NN + 1) * 4);
    int*   cursor= (int*)alloc((size_t)NN * 4);
    int*   ssrc  = (int*)alloc((size_t)EE * 4);
    int*   seid  = (int*)alloc((size_t)EE * 4);
    float* seab  = (float*)alloc((size_t)EE * 4);
    float* sbuf  = (float*)alloc(64);
    float* psum  = (float*)alloc((size_t)NG * HC * 4);
    int*   gcnt  = (int*)alloc((size_t)NG * 4);
    int*   bsum  = (int*)alloc(256 * 4);
    int*   boff  = (int*)alloc(256 * 4);

    zero_kernel<<<196, 256, 0, stream>>>(deg, easum, psum, gcnt);
    hist_kernel<<<3125, 256, 0, stream>>>(ei, ea, deg, easum, batch, gcnt);
    scan1_kernel<<<196, 256, 0, stream>>>(deg, bsum);
    scan2_kernel<<<1, 256, 0, stream>>>(bsum, boff);
    scan3_kernel<<<196, 256, 0, stream>>>(deg, boff, soff, cursor);
    scatter_kernel<<<3125, 256, 0, stream>>>(ei, ea, cursor, ssrc, seid, seab);
    preps_kernel<<<1, 64, 0, stream>>>(we1, ae1, we2, ae2, sbuf);

    gemm_kernel<128><<<3125, 160, 0, stream>>>(x, w1, as1, ad1, hbuf, als, ald);
    aggregate_kernel<<<NN, 192, 0, stream>>>(soff, ssrc, seid, seab, hbuf, als, ald,
                                             easum, sbuf, b1, ln1g, ln1b, a1, x12);

    gemm_kernel<160><<<3125, 160, 0, stream>>>(x12, w2, as2, ad2, hbuf, als, ald);
    aggregate_kernel<<<NN, 192, 0, stream>>>(soff, ssrc, seid, seab, hbuf, als, ald,
                                             easum, sbuf + 5, b2, ln2g, ln2b, a2, x12);

    gemm3_kernel<<<3125, 160, 0, stream>>>(x12, mw, mb, batch, out, psum);
    pooldiv_kernel<<<40, 256, 0, stream>>>(psum, gcnt, pooled_out);
}

// Round 3
// 718.889 us; speedup vs baseline: 1.9399x; 1.3668x over previous
//
#include <hip/hip_runtime.h>
#include <math.h>

#define NN 50000
#define EE 800000
#define FIN 128
#define NH 5
#define HC 160
#define NG 64
#define CHUNK 384
#define NB 160        // sort blocks
#define EPB 5000      // edges per sort block (NB*EPB == EE)
#define NW 12500      // packed histogram words (4 byte-bins per word)

__device__ __forceinline__ float lrelu(float x, float s) { return x >= 0.f ? x : s * x; }

// ---------------- psum zero + per-graph node counts via binary search (batch sorted)
__global__ void prep_kernel(const int* __restrict__ batch, float* psum, int* gcnt) {
    int i = blockIdx.x * 256 + threadIdx.x;
    if (i < NG * HC) psum[i] = 0.f;
    if (i < NG) {
        int lo = 0, hi = NN;
        while (lo < hi) { int m = (lo + hi) >> 1; if (batch[m] < i) lo = m + 1; else hi = m; }
        int s = lo;
        lo = 0; hi = NN;
        int g1 = i + 1;
        while (lo < hi) { int m = (lo + hi) >> 1; if (batch[m] < g1) lo = m + 1; else hi = m; }
        gcnt[i] = lo - s;
    }
}

// ---------------- per-block LDS histogram of dst (byte-packed, no global atomics)
__global__ __launch_bounds__(256) void hist_kernel(const int* __restrict__ ei,
                                                   unsigned* __restrict__ hist_g) {
    __shared__ unsigned lh[NW];
    int b = blockIdx.x, tid = threadIdx.x;
    for (int w = tid; w < NW; w += 256) lh[w] = 0;
    __syncthreads();
    const int* dstp = ei + EE + b * EPB;
    for (int i = tid; i < EPB; i += 256) {
        int d = dstp[i];
        atomicAdd(&lh[d >> 2], 1u << ((d & 3) * 8));
    }
    __syncthreads();
    unsigned* outp = hist_g + (size_t)b * NW;
    for (int w = tid; w < NW; w += 256) outp[w] = lh[w];
}

// ---------------- column scan over blocks: per-(block,bin) base + total deg
__global__ void sscan_kernel(const unsigned* __restrict__ hist_g,
                             unsigned short* __restrict__ base_g, int* __restrict__ deg) {
    int w = blockIdx.x * 256 + threadIdx.x;
    if (w >= NW) return;
    unsigned r0 = 0, r1 = 0, r2 = 0, r3 = 0;
    for (int b = 0; b < NB; b++) {
        unsigned x = hist_g[(size_t)b * NW + w];
        uint2 st;
        st.x = r0 | (r1 << 16);
        st.y = r2 | (r3 << 16);
        *reinterpret_cast<uint2*>(&base_g[(size_t)b * NN + 4 * w]) = st;
        r0 += x & 0xffu; r1 += (x >> 8) & 0xffu; r2 += (x >> 16) & 0xffu; r3 += (x >> 24) & 0xffu;
    }
    uint4 dv; dv.x = r0; dv.y = r1; dv.z = r2; dv.w = r3;
    *reinterpret_cast<uint4*>(&deg[4 * w]) = dv;
}

// ------------------------------------------------------- 3-phase parallel scan
__global__ void scan1_kernel(const int* __restrict__ deg, int* bsum) {
    __shared__ int ws[4];
    int tid = threadIdx.x, lane = tid & 63, wid = tid >> 6;
    int i = blockIdx.x * 256 + tid;
    int v = (i < NN) ? deg[i] : 0;
    for (int o = 32; o >= 1; o >>= 1) v += __shfl_down(v, o, 64);
    if (lane == 0) ws[wid] = v;
    __syncthreads();
    if (tid == 0) bsum[blockIdx.x] = ws[0] + ws[1] + ws[2] + ws[3];
}

__global__ void scan2_kernel(int* bsum, int* boff) {
    __shared__ int ws[4];
    int tid = threadIdx.x, lane = tid & 63, wid = tid >> 6;
    int v = (tid < 196) ? bsum[tid] : 0;
    int x = v;
    for (int o = 1; o < 64; o <<= 1) {
        int t = __shfl_up(x, o, 64);
        if (lane >= o) x += t;
    }
    if (lane == 63) ws[wid] = x;
    __syncthreads();
    if (tid == 0) {
        int acc = 0;
        for (int w = 0; w < 4; w++) { int t = ws[w]; ws[w] = acc; acc += t; }
    }
    __syncthreads();
    if (tid < 196) boff[tid] = x + ws[wid] - v;
}

__global__ void scan3_kernel(const int* __restrict__ deg, const int* __restrict__ boff,
                             int* off) {
    __shared__ int ws[4];
    int tid = threadIdx.x, lane = tid & 63, wid = tid >> 6;
    int i = blockIdx.x * 256 + tid;
    int v = (i < NN) ? deg[i] : 0;
    int x = v;
    for (int o = 1; o < 64; o <<= 1) {
        int t = __shfl_up(x, o, 64);
        if (lane >= o) x += t;
    }
    if (lane == 63) ws[wid] = x;
    __syncthreads();
    if (tid == 0) {
        int acc = 0;
        for (int w = 0; w < 4; w++) { int t = ws[w]; ws[w] = acc; acc += t; }
    }
    __syncthreads();
    int incl = x + ws[wid] + boff[blockIdx.x];
    if (i < NN) off[i + 1] = incl;
    if (i == 0) off[0] = 0;
}

// ---------------- rank via LDS + write packed edge record (no global atomics)
__global__ __launch_bounds__(256) void scatter_kernel(const int* __restrict__ ei,
                                                      const float* __restrict__ ea,
                                                      const unsigned short* __restrict__ base_g,
                                                      const int* __restrict__ soff,
                                                      uint4* __restrict__ erec) {
    __shared__ unsigned lc[NW];
    int b = blockIdx.x, tid = threadIdx.x;
    for (int w = tid; w < NW; w += 256) lc[w] = 0;
    __syncthreads();
    int e0 = b * EPB;
    const unsigned short* brow = base_g + (size_t)b * NN;
    for (int i = tid; i < EPB; i += 256) {
        int e = e0 + i;
        int d = ei[EE + e];
        int sh = (d & 3) * 8;
        unsigned old = atomicAdd(&lc[d >> 2], 1u << sh);
        int r = (int)((old >> sh) & 0xffu);
        int pos = soff[d] + (int)brow[d] + r;
        uint4 rec;
        rec.x = (unsigned)ei[e];
        rec.y = (unsigned)e;
        rec.z = __float_as_uint(ea[e]);
        rec.w = 0;
        erec[pos] = rec;
    }
}

// -------------------------------------- s[h] = dot(we[h*32: ], ae[h]) per layer
__global__ void preps_kernel(const float* we1, const float* ae1,
                             const float* we2, const float* ae2, float* s_out) {
    int tid = threadIdx.x;
    if (tid < 10) {
        const float* we = (tid < 5) ? we1 : we2;
        const float* ae = (tid < 5) ? ae1 : ae2;
        int h = tid % 5;
        float s = 0.f;
        for (int c = 0; c < 32; c++) s += we[h * 32 + c] * ae[h * 32 + c];
        s_out[tid] = s;
    }
}

// ---------------- h = A @ W  (K = 128 or 160), fused per-(node,head) att dots
template <int K>
__global__ __launch_bounds__(160) void gemm_kernel(const float* __restrict__ A,
                                                   const float* __restrict__ W,
                                                   const float* __restrict__ a_s,
                                                   const float* __restrict__ a_d,
                                                   float* __restrict__ out,
                                                   float* al_s, float* al_d) {
    __shared__ __align__(16) float xs[K][16];
    __shared__ float hs[16][HC + 1];
    int j = threadIdx.x;
    int base = blockIdx.x * 16;
    for (int idx = j; idx < 16 * K; idx += 160) {
        int r = idx / K, k = idx - r * K;
        xs[k][r] = A[(size_t)(base + r) * K + k];
    }
    __syncthreads();
    float acc[16];
#pragma unroll
    for (int r = 0; r < 16; r++) acc[r] = 0.f;
    for (int k = 0; k < K; k++) {
        float wv = W[k * HC + j];
        const float4* row = reinterpret_cast<const float4*>(&xs[k][0]);
        float4 q0 = row[0], q1 = row[1], q2 = row[2], q3 = row[3];
        acc[0] += q0.x * wv;  acc[1] += q0.y * wv;  acc[2] += q0.z * wv;  acc[3] += q0.w * wv;
        acc[4] += q1.x * wv;  acc[5] += q1.y * wv;  acc[6] += q1.z * wv;  acc[7] += q1.w * wv;
        acc[8] += q2.x * wv;  acc[9] += q2.y * wv;  acc[10] += q2.z * wv; acc[11] += q2.w * wv;
        acc[12] += q3.x * wv; acc[13] += q3.y * wv; acc[14] += q3.z * wv; acc[15] += q3.w * wv;
    }
#pragma unroll
    for (int r = 0; r < 16; r++) {
        out[(size_t)(base + r) * HC + j] = acc[r];
        hs[r][j] = acc[r];
    }
    __syncthreads();
    {
        int r = j / 10, rem = j - r * 10;
        int hd = rem >> 1, sd = rem & 1;
        const float* av = sd ? a_d : a_s;
        float s = 0.f;
#pragma unroll
        for (int c = 0; c < 32; c++) s += hs[r][hd * 32 + c] * av[hd * 32 + c];
        float* dst = sd ? al_d : al_s;
        dst[(base + r) * NH + hd] = s;
    }
}

// ------------- per-node: segment softmax + weighted gather + bias/lrelu/LN
__global__ __launch_bounds__(192) void aggregate_kernel(
    const int* __restrict__ soff, const uint4* __restrict__ erec,
    const float* __restrict__ hfeat, const float* __restrict__ al_s,
    const float* __restrict__ al_d, const float* __restrict__ s_e,
    const float* __restrict__ bias, const float* __restrict__ g_ln,
    const float* __restrict__ b_ln,
    float* __restrict__ alpha_out, float* __restrict__ x_out) {
    int n = blockIdx.x;
    int tid = threadIdx.x;
    int lane = tid & 63, wid = tid >> 6;
    int s0 = soff[n];
    int deg = soff[n + 1] - s0;
    int items = deg + 1;

    __shared__ float w_sh[CHUNK * NH];
    __shared__ int isrc_sh[CHUNK];
    __shared__ float sm[NH], sdinv[NH];
    __shared__ float sh_ad[NH], sh_se[NH];
    __shared__ float wred[18], wred2[15];
    __shared__ float stat[2];
    __shared__ float emean_sh;

    if (tid < NH) { sh_ad[tid] = al_d[n * NH + tid]; sh_se[tid] = s_e[tid]; }
    __syncthreads();
    float adr[NH], ser[NH];
#pragma unroll
    for (int h = 0; h < NH; h++) { adr[h] = sh_ad[h]; ser[h] = sh_se[h]; }

    float v = 0.f;

    if (items <= CHUNK) {
        // ---- pass A: real edges -> logits in LDS, per-head max, edge-attr sum
        float lm[NH];
#pragma unroll
        for (int h = 0; h < NH; h++) lm[h] = -3.0e38f;
        float eas = 0.f;
        for (int i = tid; i < deg; i += 192) {
            uint4 rec = erec[s0 + i];
            int src = (int)rec.x;
            float eav = __uint_as_float(rec.z);
            isrc_sh[i] = src;
            eas += eav;
#pragma unroll
            for (int h = 0; h < NH; h++) {
                float r = lrelu(al_s[src * NH + h] + adr[h] + eav * ser[h], 0.2f);
                w_sh[i * NH + h] = r;
                lm[h] = fmaxf(lm[h], r);
            }
        }
        for (int o = 32; o >= 1; o >>= 1) {
#pragma unroll
            for (int h = 0; h < NH; h++) lm[h] = fmaxf(lm[h], __shfl_down(lm[h], o, 64));
            eas += __shfl_down(eas, o, 64);
        }
        if (lane == 0) {
#pragma unroll
            for (int h = 0; h < NH; h++) wred[wid * 6 + h] = lm[h];
            wred[wid * 6 + 5] = eas;
        }
        __syncthreads();
        if (tid == 0) emean_sh = (wred[5] + wred[11] + wred[17]) / fmaxf((float)deg, 1.f);
        __syncthreads();
        if (tid < NH) {
            float m3 = fmaxf(fmaxf(wred[tid], wred[6 + tid]), wred[12 + tid]);
            float rs = lrelu(al_s[n * NH + tid] + sh_ad[tid] + emean_sh * sh_se[tid], 0.2f);
            w_sh[deg * NH + tid] = rs;
            sm[tid] = fmaxf(m3, rs);
        }
        if (tid == 0) isrc_sh[deg] = n;
        __syncthreads();

        // ---- pass B: exp + sum
        float ls[NH] = {0.f, 0.f, 0.f, 0.f, 0.f};
        for (int i = tid; i < items; i += 192) {
#pragma unroll
            for (int h = 0; h < NH; h++) {
                float w = expf(w_sh[i * NH + h] - sm[h]);
                w_sh[i * NH + h] = w;
                ls[h] += w;
            }
        }
        for (int o = 32; o >= 1; o >>= 1) {
#pragma unroll
            for (int h = 0; h < NH; h++) ls[h] += __shfl_down(ls[h], o, 64);
        }
        if (lane == 0) {
#pragma unroll
            for (int h = 0; h < NH; h++) wred2[wid * 5 + h] = ls[h];
        }
        __syncthreads();
        if (tid < NH) sdinv[tid] = 1.f / (wred2[tid] + wred2[5 + tid] + wred2[10 + tid]);
        __syncthreads();

        // ---- normalize + alpha writeback (item-parallel)
        for (int i = tid; i < items; i += 192) {
            int opos = (i < deg) ? (int)erec[s0 + i].y : (EE + n);
#pragma unroll
            for (int h = 0; h < NH; h++) {
                float w = w_sh[i * NH + h] * sdinv[h];
                w_sh[i * NH + h] = w;
                alpha_out[(size_t)opos * NH + h] = w;
            }
        }
        __syncthreads();

        // ---- pass C: channel-parallel weighted gather
        if (tid < HC) {
            int c = tid, hd = c >> 5;
            float acc = 0.f;
            for (int i = 0; i < items; i++) {
                acc += w_sh[i * NH + hd] * hfeat[(size_t)isrc_sh[i] * HC + c];
            }
            v = lrelu(acc + bias[c], 0.01f);
        }
    } else {
        // ---- slow path (deg >= CHUNK): streaming recompute
        float lm[NH];
#pragma unroll
        for (int h = 0; h < NH; h++) lm[h] = -3.0e38f;
        float eas = 0.f;
        for (int i = tid; i < deg; i += 192) {
            uint4 rec = erec[s0 + i];
            int src = (int)rec.x;
            float eav = __uint_as_float(rec.z);
            eas += eav;
#pragma unroll
            for (int h = 0; h < NH; h++) {
                float r = lrelu(al_s[src * NH + h] + adr[h] + eav * ser[h], 0.2f);
                lm[h] = fmaxf(lm[h], r);
            }
        }
        for (int o = 32; o >= 1; o >>= 1) {
#pragma unroll
            for (int h = 0; h < NH; h++) lm[h] = fmaxf(lm[h], __shfl_down(lm[h], o, 64));
            eas += __shfl_down(eas, o, 64);
        }
        if (lane == 0) {
#pragma unroll
            for (int h = 0; h < NH; h++) wred[wid * 6 + h] = lm[h];
            wred[wid * 6 + 5] = eas;
        }
        __syncthreads();
        if (tid == 0) emean_sh = (wred[5] + wred[11] + wred[17]) / fmaxf((float)deg, 1.f);
        __syncthreads();
        if (tid < NH) {
            float m3 = fmaxf(fmaxf(wred[tid], wred[6 + tid]), wred[12 + tid]);
            float rs = lrelu(al_s[n * NH + tid] + sh_ad[tid] + emean_sh * sh_se[tid], 0.2f);
            sm[tid] = fmaxf(m3, rs);
        }
        __syncthreads();

        float ls[NH] = {0.f, 0.f, 0.f, 0.f, 0.f};
        for (int i = tid; i < items; i += 192) {
            int src; float eav;
            if (i < deg) { uint4 rec = erec[s0 + i]; src = (int)rec.x; eav = __uint_as_float(rec.z); }
            else         { src = n; eav = emean_sh; }
#pragma unroll
            for (int h = 0; h < NH; h++) {
                float r = lrelu(al_s[src * NH + h] + adr[h] + eav * ser[h], 0.2f);
                ls[h] += expf(r - sm[h]);
            }
        }
        for (int o = 32; o >= 1; o >>= 1) {
#pragma unroll
            for (int h = 0; h < NH; h++) ls[h] += __shfl_down(ls[h], o, 64);
        }
        if (lane == 0) {
#pragma unroll
            for (int h = 0; h < NH; h++) wred2[wid * 5 + h] = ls[h];
        }
        __syncthreads();
        if (tid < NH) sdinv[tid] = 1.f / (wred2[tid] + wred2[5 + tid] + wred2[10 + tid]);
        __syncthreads();

        if (tid < HC) {
            int c = tid, hd = c >> 5;
            float mh = sm[hd], dinv = sdinv[hd], adh = sh_ad[hd], seh = sh_se[hd];
            float acc = 0.f;
            for (int i = 0; i < items; i++) {
                int src; float eav; int opos;
                if (i < deg) { uint4 rec = erec[s0 + i]; src = (int)rec.x; eav = __uint_as_float(rec.z); opos = (int)rec.y; }
                else         { src = n; eav = emean_sh; opos = EE + n; }
                float r = lrelu(al_s[src * NH + hd] + adh + eav * seh, 0.2f);
                float w = expf(r - mh) * dinv;
                if ((c & 31) == 0) alpha_out[(size_t)opos * NH + hd] = w;
                acc += w * hfeat[(size_t)src * HC + c];
            }
            v = lrelu(acc + bias[c], 0.01f);
        }
    }

    // ---- fused LayerNorm across the 160 channels
    float p1 = (tid < HC) ? v : 0.f;
    float p2 = p1 * p1;
    for (int o = 32; o >= 1; o >>= 1) {
        p1 += __shfl_down(p1, o, 64);
        p2 += __shfl_down(p2, o, 64);
    }
    if (lane == 0) { wred[wid] = p1; wred[8 + wid] = p2; }
    __syncthreads();
    if (tid == 0) {
        float s1 = wred[0] + wred[1] + wred[2];
        float s2 = wred[8] + wred[9] + wred[10];
        float mean = s1 / (float)HC;
        float var = s2 / (float)HC - mean * mean;
        stat[0] = mean;
        stat[1] = rsqrtf(var + 1e-5f);
    }
    __syncthreads();
    if (tid < HC)
        x_out[(size_t)n * HC + tid] = (v - stat[0]) * stat[1] * g_ln[tid] + b_ln[tid];
}

// -------- x3 = lrelu(x2 @ mw + mb); fused pooled partial sums (batch sorted)
__global__ __launch_bounds__(160) void gemm3_kernel(const float* A, const float* __restrict__ W,
                                                    const float* __restrict__ bias,
                                                    const int* __restrict__ batch,
                                                    float* x3, float* pooled) {
    __shared__ __align__(16) float xs[HC][16];
    __shared__ int bt[16];
    int j = threadIdx.x;
    int base = blockIdx.x * 16;
    for (int idx = j; idx < 16 * HC; idx += 160) {
        int r = idx / HC, k = idx - r * HC;
        xs[k][r] = A[(size_t)(base + r) * HC + k];
    }
    if (j < 16) bt[j] = batch[base + j];
    __syncthreads();
    float acc[16];
#pragma unroll
    for (int r = 0; r < 16; r++) acc[r] = 0.f;
    for (int k = 0; k < HC; k++) {
        float wv = W[k * HC + j];
        const float4* row = reinterpret_cast<const float4*>(&xs[k][0]);
        float4 q0 = row[0], q1 = row[1], q2 = row[2], q3 = row[3];
        acc[0] += q0.x * wv;  acc[1] += q0.y * wv;  acc[2] += q0.z * wv;  acc[3] += q0.w * wv;
        acc[4] += q1.x * wv;  acc[5] += q1.y * wv;  acc[6] += q1.z * wv;  acc[7] += q1.w * wv;
        acc[8] += q2.x * wv;  acc[9] += q2.y * wv;  acc[10] += q2.z * wv; acc[11] += q2.w * wv;
        acc[12] += q3.x * wv; acc[13] += q3.y * wv; acc[14] += q3.z * wv; acc[15] += q3.w * wv;
    }
    float bj = bias[j];
    float run = 0.f;
    int g = bt[0];
#pragma unroll
    for (int r = 0; r < 16; r++) {
        float vv = lrelu(acc[r] + bj, 0.01f);
        x3[(size_t)(base + r) * HC + j] = vv;
        int gb = bt[r];
        if (gb != g) { atomicAdd(&pooled[g * HC + j], run); run = 0.f; g = gb; }
        run += vv;
    }
    atomicAdd(&pooled[g * HC + j], run);
}

__global__ void pooldiv_kernel(const float* __restrict__ psum, const int* __restrict__ gcnt,
                               float* pooled_out) {
    int i = blockIdx.x * 256 + threadIdx.x;
    if (i < NG * HC) pooled_out[i] = psum[i] / fmaxf((float)gcnt[i / HC], 1.f);
}

// ---------------------------------------------------------------------- launch
extern "C" void kernel_launch(void* const* d_in, const int* in_sizes, int n_in,
                              void* d_out, int out_size, void* d_ws, size_t ws_size,
                              hipStream_t stream) {
    const float* x    = (const float*)d_in[0];
    const int*   ei   = (const int*)d_in[1];
    const float* ea   = (const float*)d_in[2];
    const int*   batch= (const int*)d_in[3];
    const float* w1   = (const float*)d_in[4];
    const float* we1  = (const float*)d_in[5];
    const float* as1  = (const float*)d_in[6];
    const float* ad1  = (const float*)d_in[7];
    const float* ae1  = (const float*)d_in[8];
    const float* b1   = (const float*)d_in[9];
    const float* w2   = (const float*)d_in[10];
    const float* we2  = (const float*)d_in[11];
    const float* as2  = (const float*)d_in[12];
    const float* ad2  = (const float*)d_in[13];
    const float* ae2  = (const float*)d_in[14];
    const float* b2   = (const float*)d_in[15];
    const float* ln1g = (const float*)d_in[16];
    const float* ln1b = (const float*)d_in[17];
    const float* ln2g = (const float*)d_in[18];
    const float* ln2b = (const float*)d_in[19];
    const float* mw   = (const float*)d_in[20];
    const float* mb   = (const float*)d_in[21];

    float* out = (float*)d_out;
    float* x12 = out;                                 // x1/x2 scratch in x3 region
    float* pooled_out = out + (size_t)NN * HC;
    float* a1 = pooled_out + NG * HC;
    float* a2 = a1 + (size_t)(EE + NN) * NH;

    char* wp = (char*)d_ws;
    auto alloc = [&](size_t bytes) {
        void* p = (void*)wp;
        wp += (bytes + 255) & ~(size_t)255;
        return p;
    };
    float* hbuf  = (float*)alloc((size_t)NN * HC * 4);   // 32 MB
    // hist_g/base_g overlay hbuf (dead before gemm1 writes hbuf)
    unsigned*       hist_g = (unsigned*)hbuf;                       // 8 MB
    unsigned short* base_g = (unsigned short*)((char*)hbuf + 8 * 1024 * 1024); // 16 MB
    uint4* erec  = (uint4*)alloc((size_t)EE * 16);       // 12.8 MB
    float* als   = (float*)alloc((size_t)NN * NH * 4);
    float* ald   = (float*)alloc((size_t)NN * NH * 4);
    int*   deg   = (int*)alloc((size_t)NN * 4);
    int*   soff  = (int*)alloc((size_t)(NN + 1) * 4);
    float* sbuf  = (float*)alloc(64);
    float* psum  = (float*)alloc((size_t)NG * HC * 4);
    int*   gcnt  = (int*)alloc((size_t)NG * 4);
    int*   bsum  = (int*)alloc(256 * 4);
    int*   boff  = (int*)alloc(256 * 4);

    prep_kernel<<<40, 256, 0, stream>>>(batch, psum, gcnt);
    hist_kernel<<<NB, 256, 0, stream>>>(ei, hist_g);
    sscan_kernel<<<49, 256, 0, stream>>>(hist_g, base_g, deg);
    scan1_kernel<<<196, 256, 0, stream>>>(deg, bsum);
    scan2_kernel<<<1, 256, 0, stream>>>(bsum, boff);
    scan3_kernel<<<196, 256, 0, stream>>>(deg, boff, soff);
    scatter_kernel<<<NB, 256, 0, stream>>>(ei, ea, base_g, soff, erec);
    preps_kernel<<<1, 64, 0, stream>>>(we1, ae1, we2, ae2, sbuf);

    gemm_kernel<128><<<3125, 160, 0, stream>>>(x, w1, as1, ad1, hbuf, als, ald);
    aggregate_kernel<<<NN, 192, 0, stream>>>(soff, erec, hbuf, als, ald,
                                             sbuf, b1, ln1g, ln1b, a1, x12);

    gemm_kernel<160><<<3125, 160, 0, stream>>>(x12, w2, as2, ad2, hbuf, als, ald);
    aggregate_kernel<<<NN, 192, 0, stream>>>(soff, erec, hbuf, als, ald,
                                             sbuf + 5, b2, ln2g, ln2b, a2, x12);

    gemm3_kernel<<<3125, 160, 0, stream>>>(x12, mw, mb, batch, out, psum);
    pooldiv_kernel<<<40, 256, 0, stream>>>(psum, gcnt, pooled_out);
}